// Round 18
// baseline (265.867 us; speedup 1.0000x reference)
//
#include <hip/hip_runtime.h>
#include <math.h>

#define S_LEN 2048
#define DH 64
#define BH_N 64
#define BQ 128
#define KT 64
#define NP (S_LEN / (2 * KT))   // 16 pair-iterations

typedef __attribute__((ext_vector_type(8))) short bf16x8;
typedef __attribute__((ext_vector_type(4))) float f32x4;
typedef __attribute__((ext_vector_type(4))) short s16x4;

__device__ __forceinline__ unsigned short f2bf(float f) {
  unsigned int u = __float_as_uint(f);
  u += 0x7fffu + ((u >> 16) & 1u);
  return (unsigned short)(u >> 16);
}

// lgkm-only barrier: publishes LDS, never drains the nt store queue.
__device__ __forceinline__ void lgkm_barrier() {
  __builtin_amdgcn_sched_barrier(0);
  asm volatile("s_waitcnt lgkmcnt(0)\n\ts_barrier" ::: "memory");
  __builtin_amdgcn_sched_barrier(0);
}

// R16 base (XCD swizzle + nt burst-ordered stores + T14 split staging +
// lgkm-only barriers). Change: TWO tiles per barrier period. 4 LDS slots
// (2 pairs x dbuf, 80KB), next-pair loads (64 VGPR) issued at top, two
// computes back-to-back, one cvt_write + one barrier per pair -> 16 barriers
// (was 32), and each prefetch gets 2 computes of latency cover. R10's old
// failure was 3->2 blocks/CU at 48->80KB; we're already at 2 blocks/CU, so
// the LDS growth is free now.
__global__ __launch_bounds__(256, 2)
void curve_attn_kernel(const float* __restrict__ Qg,
                       const float* __restrict__ Kg,
                       const float* __restrict__ Vg,
                       float* __restrict__ Og,
                       float* __restrict__ Wg,
                       float sc_l2e, float neg_l2C)
{
  __shared__ unsigned short ldsK[2][2][64 * 64];  // [pair][tile][k][d], swizzled
  __shared__ unsigned short ldsV[2][2][64 * 64];  // [pair][tile][d][k], swizzled
  __shared__ unsigned short ldsW[4][32 * 64];     // per-wave [q][k], swizzled

  const int tid  = threadIdx.x;
  const int lane = tid & 63;
  const int wv   = tid >> 6;
  const int lr   = lane & 15;
  const int lg   = lane >> 4;

  // XCD-aware swizzle (nwg = 1024, 8 XCDs, 128 blocks per XCD chunk)
  const int bid = (blockIdx.x & 7) * 128 + (blockIdx.x >> 3);
  const int bh  = bid >> 4;
  const int qt  = (bid & 15) * BQ;

  const size_t sd = (size_t)S_LEN * DH;
  const float* Qb = Qg + (size_t)bh * sd;
  const float* Kb = Kg + (size_t)bh * sd;
  const float* Vb = Vg + (size_t)bh * sd;
  float* Ob = Og + (size_t)bh * sd;
  float* Wb = Wg + (size_t)bh * (size_t)S_LEN * S_LEN;

  const int qrow0 = qt + wv * 32;

  // ---- Q fragments (R1 verbatim): A-frag m=lr, k=8*lg+i ----
  bf16x8 qf[2][2];
#pragma unroll
  for (int mb = 0; mb < 2; ++mb)
#pragma unroll
    for (int kb = 0; kb < 2; ++kb) {
      const float* src = Qb + (size_t)(qrow0 + mb * 16 + lr) * DH + kb * 32 + lg * 8;
      float4 a = *(const float4*)src;
      float4 b = *(const float4*)(src + 4);
      bf16x8 q;
      q[0] = (short)f2bf(a.x); q[1] = (short)f2bf(a.y);
      q[2] = (short)f2bf(a.z); q[3] = (short)f2bf(a.w);
      q[4] = (short)f2bf(b.x); q[5] = (short)f2bf(b.y);
      q[6] = (short)f2bf(b.z); q[7] = (short)f2bf(b.w);
      qf[mb][kb] = q;
    }

  f32x4 oacc[2][4];
#pragma unroll
  for (int i = 0; i < 2; ++i)
#pragma unroll
    for (int j = 0; j < 4; ++j)
      oacc[i][j] = (f32x4){0.f, 0.f, 0.f, 0.f};

  // staging thread mapping (R1 verbatim)
  const int kr = tid >> 2;          // K row 0..63
  const int kc = (tid & 3) * 4;     // K col base {0,4,8,12}
  const int vr = (tid >> 4) * 4;    // V k-row quad base
  const int vc = (tid & 15) * 4;    // V d-col quad base

  float4 kregA[4], vregA[4], kregB[4], vregB[4];  // pair prefetch (64 VGPR)

  auto load_pair = [&](int tA, int tB) {
    const float* ksA = Kb + (size_t)(tA + kr) * DH + kc;
#pragma unroll
    for (int j = 0; j < 4; ++j) kregA[j] = *(const float4*)(ksA + 16 * j);
    const float* vsA = Vb + (size_t)(tA + vr) * DH + vc;
#pragma unroll
    for (int j = 0; j < 4; ++j) vregA[j] = *(const float4*)(vsA + (size_t)j * DH);
    const float* ksB = Kb + (size_t)(tB + kr) * DH + kc;
#pragma unroll
    for (int j = 0; j < 4; ++j) kregB[j] = *(const float4*)(ksB + 16 * j);
    const float* vsB = Vb + (size_t)(tB + vr) * DH + vc;
#pragma unroll
    for (int j = 0; j < 4; ++j) vregB[j] = *(const float4*)(vsB + (size_t)j * DH);
  };

  auto cvt_write_one = [&](int pair, int slot, float4 (&kk)[4], float4 (&vv)[4]) {
#pragma unroll
    for (int j = 0; j < 4; ++j) {
      float4 v = kk[j];
      int e  = kr * 64 + kc + 16 * j;
      int se = e ^ ((kr & 7) << 3);
      s16x4 p;
      p[0] = (short)f2bf(v.x); p[1] = (short)f2bf(v.y);
      p[2] = (short)f2bf(v.z); p[3] = (short)f2bf(v.w);
      *(s16x4*)&ldsK[pair][slot][se] = p;
    }
#pragma unroll
    for (int jj = 0; jj < 4; ++jj) {
      int row = vc + jj;
      int e   = row * 64 + vr;
      int se  = e ^ ((row & 7) << 3);
      s16x4 p;
      p[0] = (short)f2bf(((const float*)&vv[0])[jj]);
      p[1] = (short)f2bf(((const float*)&vv[1])[jj]);
      p[2] = (short)f2bf(((const float*)&vv[2])[jj]);
      p[3] = (short)f2bf(((const float*)&vv[3])[jj]);
      *(s16x4*)&ldsV[pair][slot][se] = p;
    }
  };

  auto compute = [&](int pair, int slot, int kt) {
    // ---- QK^T (R11 verbatim): A=Q, B=K -> C[m=q][n=k] ----
    f32x4 sacc[2][4];
#pragma unroll
    for (int i = 0; i < 2; ++i)
#pragma unroll
      for (int j = 0; j < 4; ++j)
        sacc[i][j] = (f32x4){0.f, 0.f, 0.f, 0.f};

#pragma unroll
    for (int db = 0; db < 2; ++db) {
      bf16x8 kf[4];
#pragma unroll
      for (int nb = 0; nb < 4; ++nb) {
        int row = nb * 16 + lr;
        int e   = (row * 64 + db * 32 + lg * 8) ^ ((row & 7) << 3);
        kf[nb] = *(const bf16x8*)&ldsK[pair][slot][e];
      }
#pragma unroll
      for (int mb = 0; mb < 2; ++mb)
#pragma unroll
        for (int nb = 0; nb < 4; ++nb)
          sacc[mb][nb] = __builtin_amdgcn_mfma_f32_16x16x32_bf16(
              qf[mb][db], kf[nb], sacc[mb][nb], 0, 0, 0);
    }

    // ---- epilogue (R11 verbatim): exp; nt stores nb-inner; ldsW ----
#pragma unroll
    for (int mb = 0; mb < 2; ++mb) {
      float wvv[4][4];                      // [nb][r]
#pragma unroll
      for (int nb = 0; nb < 4; ++nb)
#pragma unroll
        for (int r = 0; r < 4; ++r)
          wvv[nb][r] = exp2f(sacc[mb][nb][r] * sc_l2e + neg_l2C);

      float* base = Wb + (size_t)(qrow0 + mb * 16 + lg * 4) * S_LEN + kt + lr;
#pragma unroll
      for (int r = 0; r < 4; ++r)
#pragma unroll
        for (int nb = 0; nb < 4; ++nb)
          __builtin_nontemporal_store(wvv[nb][r],
                                      base + (size_t)r * S_LEN + nb * 16);

#pragma unroll
      for (int nb = 0; nb < 4; ++nb)
#pragma unroll
        for (int r = 0; r < 4; ++r) {
          int row = mb * 16 + lg * 4 + r;
          int e   = (row * 64 + nb * 16 + lr) ^ ((row & 7) << 3);
          ldsW[wv][e] = f2bf(wvv[nb][r]);
        }
    }

    // ---- PV (R11 verbatim): A=W, B=V -> C[m=q][n=d] ----
#pragma unroll
    for (int kb = 0; kb < 2; ++kb) {
      bf16x8 af[2];
#pragma unroll
      for (int mb = 0; mb < 2; ++mb) {
        int row = mb * 16 + lr;
        int e   = (row * 64 + kb * 32 + lg * 8) ^ ((row & 7) << 3);
        af[mb] = *(const bf16x8*)&ldsW[wv][e];
      }
#pragma unroll
      for (int db = 0; db < 4; ++db) {
        int row = db * 16 + lr;
        int e   = (row * 64 + kb * 32 + lg * 8) ^ ((row & 7) << 3);
        bf16x8 vf = *(const bf16x8*)&ldsV[pair][slot][e];
#pragma unroll
        for (int mb = 0; mb < 2; ++mb)
          oacc[mb][db] = __builtin_amdgcn_mfma_f32_16x16x32_bf16(
              af[mb], vf, oacc[mb][db], 0, 0, 0);
      }
    }
  };

  // ---- pipeline: 2 tiles per barrier period, 16 barriers total ----
  load_pair(0, KT);
  cvt_write_one(0, 0, kregA, vregA);
  cvt_write_one(0, 1, kregB, vregB);
  lgkm_barrier();

#pragma unroll 1
  for (int g = 0; g < NP; ++g) {
    if (g + 1 < NP)
      load_pair((2 * g + 2) * KT, (2 * g + 3) * KT);  // lands over 2 computes
    compute(g & 1, 0, (2 * g) * KT);
    compute(g & 1, 1, (2 * g + 1) * KT);
    if (g + 1 < NP) {
      cvt_write_one((g + 1) & 1, 0, kregA, vregA);    // waits loads only
      cvt_write_one((g + 1) & 1, 1, kregB, vregB);
    }
    lgkm_barrier();                  // publishes LDS; nt stores keep streaming
  }

  // ---- write O (nt, R11 verbatim) ----
#pragma unroll
  for (int mb = 0; mb < 2; ++mb)
#pragma unroll
    for (int db = 0; db < 4; ++db) {
      float* dst = Ob + (size_t)(qrow0 + mb * 16 + lg * 4) * DH + db * 16 + lr;
#pragma unroll
      for (int r = 0; r < 4; ++r)
        __builtin_nontemporal_store(oacc[mb][db][r], dst + (size_t)r * DH);
    }
}

extern "C" void kernel_launch(void* const* d_in, const int* in_sizes, int n_in,
                              void* d_out, int out_size, void* d_ws, size_t ws_size,
                              hipStream_t stream) {
  const float* Q = (const float*)d_in[0];
  const float* K = (const float*)d_in[1];
  const float* V = (const float*)d_in[2];
  float* O = (float*)d_out;
  float* W = O + (size_t)BH_N * S_LEN * DH;

  const double E = 2.718281828459045235360287;
  double C = 1.0 + exp(E);
  float neg_l2C = (float)(-(log(C) / log(2.0)));
  float sc_l2e  = (float)(0.125 / log(2.0));

  curve_attn_kernel<<<dim3(BH_N * (S_LEN / BQ)), dim3(256), 0, stream>>>(
      Q, K, V, O, W, sc_l2e, neg_l2C);
}

// Round 19
// 232.587 us; speedup vs baseline: 1.1431x; 1.1431x over previous
//
#include <hip/hip_runtime.h>
#include <math.h>

#define S_LEN 2048
#define DH 64
#define BH_N 64
#define BQ 128
#define KT 64
#define NT (S_LEN / KT)

typedef __attribute__((ext_vector_type(8))) short bf16x8;
typedef __attribute__((ext_vector_type(4))) float f32x4;
typedef __attribute__((ext_vector_type(4))) short s16x4;

__device__ __forceinline__ unsigned short f2bf(float f) {
  unsigned int u = __float_as_uint(f);
  u += 0x7fffu + ((u >> 16) & 1u);
  return (unsigned short)(u >> 16);
}

// lgkm-only barrier (correctness-validated): publishes LDS writes, does NOT
// drain vmcnt -> nt stores stream across tile boundaries.
__device__ __forceinline__ void lgkm_barrier() {
  __builtin_amdgcn_sched_barrier(0);
  asm volatile("s_waitcnt lgkmcnt(0)\n\ts_barrier" ::: "memory");
  __builtin_amdgcn_sched_barrier(0);
}

// R16 FINAL (best: 233.6 us). XCD-aware swizzle + nt burst-ordered W/O
// stores + dbuf + T14 split staging (loads issue-early at top of iteration,
// cvt+ds_write after compute waits only on those loads via in-order vmcnt)
// + lgkm-only barriers. Probed and rejected: wider tiles/prefetch (R7/R18),
// occupancy changes (R5/R8), K-from-global (R14), swapped QK^T store width
// (R13), fill-shaped LDS-roundtrip stores (R17), pair barriers (R18).
__global__ __launch_bounds__(256, 2)
void curve_attn_kernel(const float* __restrict__ Qg,
                       const float* __restrict__ Kg,
                       const float* __restrict__ Vg,
                       float* __restrict__ Og,
                       float* __restrict__ Wg,
                       float sc_l2e, float neg_l2C)
{
  __shared__ unsigned short ldsK[2][64 * 64];   // [buf][k_local][d], swizzled
  __shared__ unsigned short ldsV[2][64 * 64];   // [buf][d][k_local], swizzled
  __shared__ unsigned short ldsW[4][32 * 64];   // per-wave [q_local][k_local], swizzled

  const int tid  = threadIdx.x;
  const int lane = tid & 63;
  const int wv   = tid >> 6;
  const int lr   = lane & 15;
  const int lg   = lane >> 4;

  // XCD-aware swizzle (nwg = 1024, 8 XCDs, 128 blocks per XCD chunk)
  const int bid = (blockIdx.x & 7) * 128 + (blockIdx.x >> 3);
  const int bh  = bid >> 4;
  const int qt  = (bid & 15) * BQ;

  const size_t sd = (size_t)S_LEN * DH;
  const float* Qb = Qg + (size_t)bh * sd;
  const float* Kb = Kg + (size_t)bh * sd;
  const float* Vb = Vg + (size_t)bh * sd;
  float* Ob = Og + (size_t)bh * sd;
  float* Wb = Wg + (size_t)bh * (size_t)S_LEN * S_LEN;

  const int qrow0 = qt + wv * 32;

  // ---- Q fragments: A-frag m=lr, k=8*lg+i ----
  bf16x8 qf[2][2];
#pragma unroll
  for (int mb = 0; mb < 2; ++mb)
#pragma unroll
    for (int kb = 0; kb < 2; ++kb) {
      const float* src = Qb + (size_t)(qrow0 + mb * 16 + lr) * DH + kb * 32 + lg * 8;
      float4 a = *(const float4*)src;
      float4 b = *(const float4*)(src + 4);
      bf16x8 q;
      q[0] = (short)f2bf(a.x); q[1] = (short)f2bf(a.y);
      q[2] = (short)f2bf(a.z); q[3] = (short)f2bf(a.w);
      q[4] = (short)f2bf(b.x); q[5] = (short)f2bf(b.y);
      q[6] = (short)f2bf(b.z); q[7] = (short)f2bf(b.w);
      qf[mb][kb] = q;
    }

  f32x4 oacc[2][4];
#pragma unroll
  for (int i = 0; i < 2; ++i)
#pragma unroll
    for (int j = 0; j < 4; ++j)
      oacc[i][j] = (f32x4){0.f, 0.f, 0.f, 0.f};

  // staging thread mapping
  const int kr = tid >> 2;          // K row 0..63
  const int kc = (tid & 3) * 4;     // K col base {0,4,8,12}
  const int vr = (tid >> 4) * 4;    // V k-row quad base
  const int vc = (tid & 15) * 4;    // V d-col quad base

  float4 kreg[4], vreg[4];          // prefetch state (+32 VGPR)

  auto load_regs = [&](int t0) {
    const float* ks = Kb + (size_t)(t0 + kr) * DH + kc;
#pragma unroll
    for (int j = 0; j < 4; ++j) kreg[j] = *(const float4*)(ks + 16 * j);
    const float* vs = Vb + (size_t)(t0 + vr) * DH + vc;
#pragma unroll
    for (int j = 0; j < 4; ++j) vreg[j] = *(const float4*)(vs + (size_t)j * DH);
  };

  auto cvt_write = [&](int buf) {
    // K tile
#pragma unroll
    for (int j = 0; j < 4; ++j) {
      float4 v = kreg[j];
      int e  = kr * 64 + kc + 16 * j;
      int se = e ^ ((kr & 7) << 3);
      s16x4 p;
      p[0] = (short)f2bf(v.x); p[1] = (short)f2bf(v.y);
      p[2] = (short)f2bf(v.z); p[3] = (short)f2bf(v.w);
      *(s16x4*)&ldsK[buf][se] = p;
    }
    // V tile transposed
#pragma unroll
    for (int jj = 0; jj < 4; ++jj) {
      int row = vc + jj;
      int e   = row * 64 + vr;
      int se  = e ^ ((row & 7) << 3);
      s16x4 p;
      p[0] = (short)f2bf(((const float*)&vreg[0])[jj]);
      p[1] = (short)f2bf(((const float*)&vreg[1])[jj]);
      p[2] = (short)f2bf(((const float*)&vreg[2])[jj]);
      p[3] = (short)f2bf(((const float*)&vreg[3])[jj]);
      *(s16x4*)&ldsV[buf][se] = p;
    }
  };

  auto compute = [&](int buf, int kt) {
    // ---- QK^T: A=Q, B=K -> C[m=q][n=k] ----
    f32x4 sacc[2][4];
#pragma unroll
    for (int i = 0; i < 2; ++i)
#pragma unroll
      for (int j = 0; j < 4; ++j)
        sacc[i][j] = (f32x4){0.f, 0.f, 0.f, 0.f};

#pragma unroll
    for (int db = 0; db < 2; ++db) {
      bf16x8 kf[4];
#pragma unroll
      for (int nb = 0; nb < 4; ++nb) {
        int row = nb * 16 + lr;
        int e   = (row * 64 + db * 32 + lg * 8) ^ ((row & 7) << 3);
        kf[nb] = *(const bf16x8*)&ldsK[buf][e];
      }
#pragma unroll
      for (int mb = 0; mb < 2; ++mb)
#pragma unroll
        for (int nb = 0; nb < 4; ++nb)
          sacc[mb][nb] = __builtin_amdgcn_mfma_f32_16x16x32_bf16(
              qf[mb][db], kf[nb], sacc[mb][nb], 0, 0, 0);
    }

    // ---- epilogue: exp; nt stores nb-inner (burst-shaped); ldsW ----
#pragma unroll
    for (int mb = 0; mb < 2; ++mb) {
      float wvv[4][4];                      // [nb][r]
#pragma unroll
      for (int nb = 0; nb < 4; ++nb)
#pragma unroll
        for (int r = 0; r < 4; ++r)
          wvv[nb][r] = exp2f(sacc[mb][nb][r] * sc_l2e + neg_l2C);

      float* base = Wb + (size_t)(qrow0 + mb * 16 + lg * 4) * S_LEN + kt + lr;
#pragma unroll
      for (int r = 0; r < 4; ++r)
#pragma unroll
        for (int nb = 0; nb < 4; ++nb)
          __builtin_nontemporal_store(wvv[nb][r],
                                      base + (size_t)r * S_LEN + nb * 16);

#pragma unroll
      for (int nb = 0; nb < 4; ++nb)
#pragma unroll
        for (int r = 0; r < 4; ++r) {
          int row = mb * 16 + lg * 4 + r;
          int e   = (row * 64 + nb * 16 + lr) ^ ((row & 7) << 3);
          ldsW[wv][e] = f2bf(wvv[nb][r]);
        }
    }

    // ---- PV: A=W, B=V -> C[m=q][n=d] ----
#pragma unroll
    for (int kb = 0; kb < 2; ++kb) {
      bf16x8 af[2];
#pragma unroll
      for (int mb = 0; mb < 2; ++mb) {
        int row = mb * 16 + lr;
        int e   = (row * 64 + kb * 32 + lg * 8) ^ ((row & 7) << 3);
        af[mb] = *(const bf16x8*)&ldsW[wv][e];
      }
#pragma unroll
      for (int db = 0; db < 4; ++db) {
        int row = db * 16 + lr;
        int e   = (row * 64 + kb * 32 + lg * 8) ^ ((row & 7) << 3);
        bf16x8 vf = *(const bf16x8*)&ldsV[buf][e];
#pragma unroll
        for (int mb = 0; mb < 2; ++mb)
          oacc[mb][db] = __builtin_amdgcn_mfma_f32_16x16x32_bf16(
              af[mb], vf, oacc[mb][db], 0, 0, 0);
      }
    }
  };

  // ---- pipeline: loads issue-early, LDS write-late, lgkm-only barriers ----
  load_regs(0);
  cvt_write(0);
  lgkm_barrier();

#pragma unroll 1
  for (int t = 0; t < NT; ++t) {
    if (t + 1 < NT)
      load_regs((t + 1) * KT);       // fire-and-forget; lands during compute
    compute(t & 1, t * KT);
    if (t + 1 < NT)
      cvt_write((t + 1) & 1);        // waits loads only (younger stores fly)
    lgkm_barrier();                  // publishes LDS; nt stores keep streaming
  }

  // ---- write O (nt) ----
#pragma unroll
  for (int mb = 0; mb < 2; ++mb)
#pragma unroll
    for (int db = 0; db < 4; ++db) {
      float* dst = Ob + (size_t)(qrow0 + mb * 16 + lg * 4) * DH + db * 16 + lr;
#pragma unroll
      for (int r = 0; r < 4; ++r)
        __builtin_nontemporal_store(oacc[mb][db][r], dst + (size_t)r * DH);
    }
}

extern "C" void kernel_launch(void* const* d_in, const int* in_sizes, int n_in,
                              void* d_out, int out_size, void* d_ws, size_t ws_size,
                              hipStream_t stream) {
  const float* Q = (const float*)d_in[0];
  const float* K = (const float*)d_in[1];
  const float* V = (const float*)d_in[2];
  float* O = (float*)d_out;
  float* W = O + (size_t)BH_N * S_LEN * DH;

  const double E = 2.718281828459045235360287;
  double C = 1.0 + exp(E);
  float neg_l2C = (float)(-(log(C) / log(2.0)));
  float sc_l2e  = (float)(0.125 / log(2.0));

  curve_attn_kernel<<<dim3(BH_N * (S_LEN / BQ)), dim3(256), 0, stream>>>(
      Q, K, V, O, W, sc_l2e, neg_l2C);
}